// Round 34
// baseline (239.497 us; speedup 1.0000x reference)
//
#include <hip/hip_runtime.h>
#include <hip/hip_bf16.h>
#include <stdint.h>
#include <string.h>

// ---------------------------------------------------------------------------
// Problem constants
// ---------------------------------------------------------------------------
#define NB   8
#define NV   2048
#define NN   20      // NEIGHBOR_NUM
#define SUP  7       // SUPPORT
#define K0   32
#define C1   64
#define C2   256
#define NV2  256     // vertices after pooling 1
#define NP2  16      // vertices after pooling 2
#define COLL_CAP 320

// ---------------------------------------------------------------------------
// Permutations (proven R21..R33)
// ---------------------------------------------------------------------------
typedef unsigned __int128 u128;

struct CPcg { u128 state; u128 inc; bool has32; uint32_t cached; };

constexpr u128 PCG_MULT = (((u128)2549297995355413924ULL) << 64) | 4865540595714422341ULL;

constexpr uint64_t c_rotr64(uint64_t v, unsigned r) {
    return (v >> (r & 63u)) | (v << ((64u - r) & 63u));
}
constexpr uint64_t pcg_next64(CPcg& g) {
    g.state = g.state * PCG_MULT + g.inc;
    uint64_t hi = (uint64_t)(g.state >> 64);
    uint64_t lo = (uint64_t)g.state;
    return c_rotr64(hi ^ lo, (unsigned)(hi >> 58));
}
constexpr uint32_t pcg_next32(CPcg& g) {
    if (g.has32) { g.has32 = false; return g.cached; }
    uint64_t n = pcg_next64(g);
    g.has32 = true;
    g.cached = (uint32_t)(n >> 32);
    return (uint32_t)n;
}
constexpr uint64_t rand_interval(CPcg& g, uint64_t mx) {
    if (mx == 0) return 0;
    uint64_t mask = mx;
    mask |= mask >> 1; mask |= mask >> 2; mask |= mask >> 4;
    mask |= mask >> 8; mask |= mask >> 16; mask |= mask >> 32;
    uint64_t v = 0;
    while ((v = ((uint64_t)pcg_next32(g) & mask)) > mx) {
    }
    return v;
}
constexpr uint32_t hashmix(uint32_t value, uint32_t& hc) {
    value ^= hc; hc *= 0x931e8875u; value *= hc; value ^= value >> 16; return value;
}
constexpr uint32_t mixpool(uint32_t x, uint32_t y) {
    uint32_t r = (x * 0xca01f9ddu) - (y * 0x4973f715u);
    r ^= r >> 16; return r;
}
constexpr CPcg make_rng(uint32_t entropy) {
    uint32_t pool[4] = {0, 0, 0, 0};
    uint32_t hc = 0x43b0d7e5u;
    for (int i = 0; i < 4; i++) {
        uint32_t v = (i == 0) ? entropy : 0u;
        pool[i] = hashmix(v, hc);
    }
    for (int isrc = 0; isrc < 4; isrc++)
        for (int idst = 0; idst < 4; idst++)
            if (isrc != idst) pool[idst] = mixpool(pool[idst], hashmix(pool[isrc], hc));
    uint32_t w[8] = {};
    uint32_t hb = 0x8b51f9ddu;
    for (int i = 0; i < 8; i++) {
        uint32_t dv = pool[i & 3];
        dv ^= hb; hb *= 0x58f38dedu; dv *= hb; dv ^= dv >> 16; w[i] = dv;
    }
    uint64_t sd[4] = {};
    for (int k = 0; k < 4; k++) sd[k] = (uint64_t)w[2 * k] | ((uint64_t)w[2 * k + 1] << 32);
    u128 s = (((u128)sd[0]) << 64) | sd[1];
    u128 iq = (((u128)sd[2]) << 64) | sd[3];
    CPcg g{};
    g.state = 0;
    g.inc = (iq << 1) | 1;
    g.state = g.state * PCG_MULT + g.inc;
    g.state += s;
    g.state = g.state * PCG_MULT + g.inc;
    g.has32 = false; g.cached = 0;
    return g;
}

struct PermOut { int p1[256]; int p2[16]; };

constexpr PermOut compute_perms() {
    PermOut o{};
    {
        CPcg g = make_rng(1u);
        int arr[2048] = {};
        for (int i = 0; i < 2048; i++) arr[i] = i;
        for (int i = 2047; i >= 1; i--) {
            int j = (int)rand_interval(g, (uint64_t)i);
            int t = arr[i]; arr[i] = arr[j]; arr[j] = t;
        }
        for (int i = 0; i < 256; i++) o.p1[i] = arr[i];
    }
    {
        CPcg g = make_rng(2u);
        int arr[256] = {};
        for (int i = 0; i < 256; i++) arr[i] = i;
        for (int i = 255; i >= 1; i--) {
            int j = (int)rand_interval(g, (uint64_t)i);
            int t = arr[i]; arr[i] = arr[j]; arr[j] = t;
        }
        for (int i = 0; i < 16; i++) o.p2[i] = arr[i];
    }
    return o;
}

struct PermArg1 { int v[256]; };
struct PermArg2 { int v[16]; };

// ---------------------------------------------------------------------------
// K0: v2 (outputs[0]) = verts[:, p1[p2[j]], :] — f32
// ---------------------------------------------------------------------------
__global__ __launch_bounds__(384) void v2_kernel(const float* __restrict__ verts,
                                                 float* __restrict__ out,
                                                 PermArg2 cidx) {
    int t = threadIdx.x;
    if (t < NB * NP2 * 3) {
        int b = t / (NP2 * 3);
        int rem = t - b * (NP2 * 3);
        int j = rem / 3;
        int c = rem - j * 3;
        out[t] = verts[(b * NV + cidx.v[j]) * 3 + c];
    }
}

// ---------------------------------------------------------------------------
// KNN linear-bucket select, COOPERATIVE (R34): all 4 waves share one row.
// Per-wave candidate slice = N/4 -> key[CPL=N/256] = 8 regs (kills the
// key[32] scratch spill seen in R30-R33: WRITE 38.5 MB -> ~0). svq packs
// (x,y,z,qj) so one ds_read_b128 serves coords+norm; qj precomputed with the
// identical left-assoc expression -> dist bit-identical to reference.
// Shared hist/coll/cnt; per-wave redundant scan (proven R26 code).
// ---------------------------------------------------------------------------
template<int N, int CPL>
__global__ __launch_bounds__(256, 4) void knn_coop_kernel(const float* __restrict__ verts,
                                                          int* __restrict__ nbr) {
    __shared__ float4 svq[N];
    __shared__ int hist[256];
    __shared__ unsigned long long coll[COLL_CAP];
    __shared__ int cnt;
    __shared__ unsigned wred[8];

    constexpr int RPB = 4;
    int bpb = N / RPB;
    int b = blockIdx.x / bpb;
    int rbase = (blockIdx.x % bpb) * RPB;
    const float* vb = verts + (size_t)b * N * 3;

    for (int t = threadIdx.x; t < N; t += 256) {
        float x = vb[t * 3 + 0], y = vb[t * 3 + 1], z = vb[t * 3 + 2];
        svq[t] = make_float4(x, y, z, x * x + y * y + z * z);  // same expr order
    }
    __syncthreads();

    int wid = threadIdx.x >> 6, lane = threadIdx.x & 63;

    for (int rr = 0; rr < RPB; rr++) {
        int i = rbase + rr;
        float4 vi = svq[i];
        float vx = vi.x, vy = vi.y, vz = vi.z;
        float qi = vi.w;

        hist[threadIdx.x] = 0;
        if (threadIdx.x == 0) cnt = 0;
        __syncthreads();

        unsigned key[CPL];
        unsigned lmin = 0xFFFFFFFFu, lmax = 0u;
        #pragma unroll
        for (int t = 0; t < CPL; t++) {
            int j = wid * (CPL * 64) + t * 64 + lane;
            float4 vj = svq[j];
            float inner = vx * vj.x + vy * vj.y + vz * vj.z;
            float dist = (-2.0f * inner + qi) + vj.w;   // same expr as reference
            unsigned u = __float_as_uint(dist);
            u = (u & 0x80000000u) ? ~u : (u | 0x80000000u);  // monotone map
            if (j == i) u = 0xFFFFFFFFu;                      // self sentinel
            key[t] = u;
            if (u != 0xFFFFFFFFu) {
                lmin = (u < lmin) ? u : lmin;
                lmax = (u > lmax) ? u : lmax;
            }
        }
        #pragma unroll
        for (int off = 32; off >= 1; off >>= 1) {
            unsigned o1 = (unsigned)__shfl_xor((int)lmin, off);
            unsigned o2 = (unsigned)__shfl_xor((int)lmax, off);
            lmin = (o1 < lmin) ? o1 : lmin;
            lmax = (o2 > lmax) ? o2 : lmax;
        }
        if (lane == 0) { wred[wid] = lmin; wred[4 + wid] = lmax; }
        __syncthreads();
        lmin = wred[0];
        lmax = wred[4];
        #pragma unroll
        for (int w = 1; w < 4; w++) {
            lmin = (wred[w] < lmin) ? wred[w] : lmin;
            lmax = (wred[4 + w] > lmax) ? wred[4 + w] : lmax;
        }
        float scale = (lmax > lmin) ? 255.0f / (float)(lmax - lmin) : 0.0f;

        #pragma unroll
        for (int t = 0; t < CPL; t++) {
            int bi = (key[t] == 0xFFFFFFFFu) ? 255
                     : (int)((float)(key[t] - lmin) * scale);
            bi = (bi > 255) ? 255 : bi;
            atomicAdd(&hist[bi], 1);
        }
        __syncthreads();

        // per-wave redundant boundary search (identical result in all waves)
        int h0 = hist[lane * 4 + 0];
        int h1 = hist[lane * 4 + 1];
        int h2 = hist[lane * 4 + 2];
        int h3 = hist[lane * 4 + 3];
        int s = h0 + h1 + h2 + h3;
        int cum = s;
        #pragma unroll
        for (int off = 1; off < 64; off <<= 1) {
            int v = __shfl_up(cum, off);
            if (lane >= off) cum += v;
        }
        unsigned long long bal = __ballot(cum >= NN);
        int L = __ffsll((long long)bal) - 1;
        int baseL = __shfl(cum, L) - __shfl(s, L);
        int g0 = __shfl(h0, L), g1 = __shfl(h1, L), g2 = __shfl(h2, L);
        int B;
        if (baseL + g0 >= NN)            B = 4 * L + 0;
        else if (baseL + g0 + g1 >= NN)  B = 4 * L + 1;
        else if (baseL + g0 + g1 + g2 >= NN) B = 4 * L + 2;
        else                              B = 4 * L + 3;

        #pragma unroll
        for (int t = 0; t < CPL; t++) {
            int bi = (key[t] == 0xFFFFFFFFu) ? 255
                     : (int)((float)(key[t] - lmin) * scale);
            bi = (bi > 255) ? 255 : bi;
            if (bi <= B) {
                int pos = atomicAdd(&cnt, 1);
                if (pos < COLL_CAP) {
                    int j = wid * (CPL * 64) + t * 64 + lane;
                    coll[pos] = ((unsigned long long)key[t] << 32) | (unsigned)j;
                }
            }
        }
        __syncthreads();
        int count = cnt;
        if (count > COLL_CAP) count = COLL_CAP;

        int* dst = nbr + ((size_t)b * N + i) * NN;
        for (int e = threadIdx.x; e < count; e += 256) {
            unsigned long long me = coll[e];
            int rank = 0;
            for (int m = 0; m < count; m++) rank += (coll[m] < me);
            if (rank < NN) dst[rank] = (int)(me & 0xFFFFFFFFull);
        }
        __syncthreads();
    }
}

// ---------------------------------------------------------------------------
// K2: operator3d + relu -> fm0 (8,2048,32). One thread per vertex.
// ---------------------------------------------------------------------------
__global__ __launch_bounds__(256) void op3d_kernel(const float* __restrict__ verts,
                                                   const int* __restrict__ nbr,
                                                   const float* __restrict__ w0w,
                                                   const float* __restrict__ w0d,
                                                   float* __restrict__ fm0) {
    __shared__ float swd[3 * SUP * K0];
    __shared__ float sww[SUP * K0];
    for (int t = threadIdx.x; t < 3 * SUP * K0; t += 256) swd[t] = w0d[t];
    for (int t = threadIdx.x; t < SUP * K0; t += 256) sww[t] = w0w[t];
    __syncthreads();

    int gid = blockIdx.x * 256 + threadIdx.x;
    int b = gid >> 11, v = gid & (NV - 1);
    const float* vb = verts + b * NV * 3;
    float vx = vb[v * 3], vy = vb[v * 3 + 1], vz = vb[v * 3 + 2];

    const int* nb = nbr + gid * NN;
    float dx[NN], dy[NN], dz[NN];
    #pragma unroll
    for (int n = 0; n < NN; n++) {
        int j = nb[n];
        dx[n] = vb[j * 3 + 0] - vx;
        dy[n] = vb[j * 3 + 1] - vy;
        dz[n] = vb[j * 3 + 2] - vz;
    }
    float* out = fm0 + gid * K0;
    #pragma unroll 1
    for (int k = 0; k < K0; k++) {
        float acc = 0.f;
        #pragma unroll
        for (int s = 0; s < SUP; s++) {
            float w0 = swd[0 * 224 + s * K0 + k];
            float w1 = swd[1 * 224 + s * K0 + k];
            float w2 = swd[2 * 224 + s * K0 + k];
            float m = 0.f;
            #pragma unroll
            for (int n = 0; n < NN; n++) {
                float t = dx[n] * w0 + dy[n] * w1 + dz[n] * w2;
                t = fmaxf(t, 0.f);
                m = fmaxf(m, t);
            }
            acc += m * sww[s * K0 + k];
        }
        out[k] = fmaxf(acc, 0.f);
    }
}

// ---------------------------------------------------------------------------
// feat GEMM (R27, proven)
// ---------------------------------------------------------------------------
template<int K, int N>
__global__ __launch_bounds__(256) void feat_gemm(const float* __restrict__ fm,
                                                 const float* __restrict__ w,
                                                 const float* __restrict__ bias,
                                                 float* __restrict__ feat) {
    __shared__ float sf[64][K];
    __shared__ float swt[K][64];
    int cb = blockIdx.x % (N / 64), rb = blockIdx.x / (N / 64);
    int r0 = rb * 64, c0 = cb * 64;

    for (int t = threadIdx.x; t < 64 * K; t += 256)
        sf[t / K][t % K] = fm[(size_t)(r0 + t / K) * K + (t % K)];
    for (int t = threadIdx.x; t < K * 64; t += 256)
        swt[t >> 6][t & 63] = w[(size_t)(t >> 6) * N + c0 + (t & 63)];
    __syncthreads();

    int col = threadIdx.x & 63, rg = threadIdx.x >> 6;
    float bv = bias[c0 + col];
    float acc[16];
    #pragma unroll
    for (int r = 0; r < 16; r++) acc[r] = bv;
    #pragma unroll 1
    for (int k = 0; k < K; k++) {
        float wk = swt[k][col];
        #pragma unroll
        for (int r = 0; r < 16; r++) acc[r] += sf[rg * 16 + r][k] * wk;
    }
    #pragma unroll
    for (int r = 0; r < 16; r++)
        feat[(size_t)(r0 + rg * 16 + r) * N + c0 + col] = acc[r];
}

// ---------------------------------------------------------------------------
// opnd1 gather-max (n-outer, unroll 4) + XCD swizzle (R33, proven)
// ---------------------------------------------------------------------------
__global__ __launch_bounds__(256) void opnd1_gather(const float* __restrict__ verts,
                                                    const int* __restrict__ nbr,
                                                    const float* __restrict__ feat1,
                                                    const float* __restrict__ w1d,
                                                    float* __restrict__ fm1) {
    __shared__ float swd[3 * SUP * C1];
    for (int t = threadIdx.x; t < 3 * SUP * C1; t += 256) swd[t] = w1d[t];
    __syncthreads();

    int wid = threadIdx.x >> 6, lane = threadIdx.x & 63;
    int b = blockIdx.x & 7;
    int vtx = b * NV + (blockIdx.x >> 3) * 4 + wid;
    int v = vtx & (NV - 1);
    const float* vb = verts + b * NV * 3;
    const int* nb = nbr + vtx * NN;
    float vx = vb[v * 3], vy = vb[v * 3 + 1], vz = vb[v * 3 + 2];

    float w0r[SUP], w1r[SUP], w2r[SUP];
    #pragma unroll
    for (int ss = 0; ss < SUP; ss++) {
        w0r[ss] = swd[0 * (SUP * C1) + ss * C1 + lane];
        w1r[ss] = swd[1 * (SUP * C1) + ss * C1 + lane];
        w2r[ss] = swd[2 * (SUP * C1) + ss * C1 + lane];
    }

    const float* fb = feat1 + (size_t)b * NV * (8 * C1);
    float m[SUP];
    #pragma unroll
    for (int ss = 0; ss < SUP; ss++) m[ss] = -3.4e38f;

    #pragma unroll 4
    for (int n = 0; n < NN; n++) {
        int j = nb[n];
        float dx = vb[j * 3 + 0] - vx;
        float dy = vb[j * 3 + 1] - vy;
        float dz = vb[j * 3 + 2] - vz;
        const float* row = fb + (size_t)j * (8 * C1) + C1 + lane;
        #pragma unroll
        for (int ss = 0; ss < SUP; ss++) {
            float th = fmaxf(dx * w0r[ss] + dy * w1r[ss] + dz * w2r[ss], 0.f);
            m[ss] = fmaxf(m[ss], th * row[ss * C1]);
        }
    }
    float fcen = fb[(size_t)v * (8 * C1) + lane];
    float total = 0.f;
    #pragma unroll
    for (int ss = 0; ss < SUP; ss++) total += m[ss];
    fm1[vtx * C1 + lane] = fmaxf(fcen + total, 0.f);
}

// ---------------------------------------------------------------------------
// opnd2 gather-max: one wave per (vertex, jj) + XCD swizzle (R33, proven)
// ---------------------------------------------------------------------------
__global__ __launch_bounds__(256) void opnd2_gather(const float* __restrict__ v1,
                                                    const int* __restrict__ nbr2,
                                                    const float* __restrict__ feat2,
                                                    const float* __restrict__ w2d,
                                                    float* __restrict__ fm2) {
    __shared__ float swd[3 * SUP * C2];
    for (int t = threadIdx.x; t < 3 * SUP * C2; t += 256) swd[t] = w2d[t];
    __syncthreads();

    int jj = threadIdx.x >> 6, lane = threadIdx.x & 63;
    int b = blockIdx.x & 7;
    int v = blockIdx.x >> 3;
    int vtx = b * NV2 + v;
    const float* vb = v1 + b * NV2 * 3;
    const int* nb = nbr2 + vtx * NN;
    float vx = vb[v * 3], vy = vb[v * 3 + 1], vz = vb[v * 3 + 2];

    int cj = jj * 64 + lane;
    float w0r[SUP], w1r[SUP], w2r[SUP];
    #pragma unroll
    for (int ss = 0; ss < SUP; ss++) {
        w0r[ss] = swd[0 * (SUP * C2) + ss * C2 + cj];
        w1r[ss] = swd[1 * (SUP * C2) + ss * C2 + cj];
        w2r[ss] = swd[2 * (SUP * C2) + ss * C2 + cj];
    }
    const float* fb = feat2 + (size_t)b * NV2 * (8 * C2);

    float m[SUP];
    #pragma unroll
    for (int ss = 0; ss < SUP; ss++) m[ss] = -3.4e38f;

    #pragma unroll 4
    for (int n = 0; n < NN; n++) {
        int j = nb[n];
        float dx = vb[j * 3 + 0] - vx;
        float dy = vb[j * 3 + 1] - vy;
        float dz = vb[j * 3 + 2] - vz;
        const float* row = fb + (size_t)j * (8 * C2) + C2 + cj;
        #pragma unroll
        for (int ss = 0; ss < SUP; ss++) {
            float th = fmaxf(dx * w0r[ss] + dy * w1r[ss] + dz * w2r[ss], 0.f);
            m[ss] = fmaxf(m[ss], th * row[ss * C2]);
        }
    }
    float total = 0.f;
    #pragma unroll
    for (int ss = 0; ss < SUP; ss++) total += m[ss];
    float fcen = fb[(size_t)v * (8 * C2) + cj];
    fm2[(size_t)vtx * C2 + cj] = fmaxf(fcen + total, 0.f);
}

// ---------------------------------------------------------------------------
// K5: pooling 1 -> v1, fm1p. One wave per sampled vertex.
// ---------------------------------------------------------------------------
__global__ __launch_bounds__(256) void pool1_kernel(const float* __restrict__ verts,
                                                    const int* __restrict__ nbr1,
                                                    const float* __restrict__ fm1,
                                                    float* __restrict__ v1,
                                                    float* __restrict__ fm1p,
                                                    PermArg1 pa) {
    int wid = threadIdx.x >> 6, lane = threadIdx.x & 63;
    int gid = blockIdx.x * 4 + wid;
    int b = gid >> 8, p = gid & 255;
    int sv = pa.v[p];
    const int* nb = nbr1 + (b * NV + sv) * NN;
    float m = -3.4e38f;
    #pragma unroll
    for (int n = 0; n < 8; n++) {
        m = fmaxf(m, fm1[(b * NV + nb[n]) * C1 + lane]);
    }
    fm1p[gid * C1 + lane] = m;
    if (lane < 3) v1[gid * 3 + lane] = verts[(b * NV + sv) * 3 + lane];
}

// ---------------------------------------------------------------------------
// K9: pooling 2 -> fm3 (outputs[1]) — f32
// ---------------------------------------------------------------------------
__global__ __launch_bounds__(256) void pool2_kernel(const int* __restrict__ nbr2,
                                                    const float* __restrict__ fm2,
                                                    float* __restrict__ out,
                                                    PermArg2 pa) {
    int wid = threadIdx.x >> 6, lane = threadIdx.x & 63;
    int gid = blockIdx.x * 4 + wid;
    int b = gid >> 4, p = gid & 15;
    int sv = pa.v[p];
    const int* nb = nbr2 + (b * NV2 + sv) * NN;
    #pragma unroll 1
    for (int jj = 0; jj < 4; jj++) {
        int c = lane + jj * 64;
        float m = -3.4e38f;
        #pragma unroll
        for (int n = 0; n < 16; n++) {
            m = fmaxf(m, fm2[(b * NV2 + nb[n]) * C2 + c]);
        }
        out[NB * NP2 * 3 + gid * C2 + c] = m;
    }
}

// ---------------------------------------------------------------------------
// Launch
// ---------------------------------------------------------------------------
extern "C" void kernel_launch(void* const* d_in, const int* in_sizes, int n_in,
                              void* d_out, int out_size, void* d_ws, size_t ws_size,
                              hipStream_t stream) {
    (void)in_sizes; (void)n_in; (void)out_size; (void)ws_size;
    const float* verts = (const float*)d_in[0];
    const float* w0w = (const float*)d_in[1];
    const float* w0d = (const float*)d_in[2];
    const float* w1w = (const float*)d_in[3];
    const float* w1b = (const float*)d_in[4];
    const float* w1d = (const float*)d_in[5];
    const float* w2w = (const float*)d_in[6];
    const float* w2b = (const float*)d_in[7];
    const float* w2d = (const float*)d_in[8];
    float* out = (float*)d_out;

    static const PermOut perms = compute_perms();

    PermArg1 pa1;
    PermArg2 pa2, pac;
    memcpy(pa1.v, perms.p1, sizeof(pa1.v));
    memcpy(pa2.v, perms.p2, sizeof(pa2.v));
    for (int j = 0; j < 16; j++) pac.v[j] = perms.p1[perms.p2[j]];

    char* ws = (char*)d_ws;
    size_t off = 0;
    auto alloc = [&](size_t bytes) -> void* {
        void* p = ws + off;
        off += (bytes + 255) & ~(size_t)255;
        return p;
    };
    int*   nbr1  = (int*)  alloc((size_t)NB * NV * NN * 4);
    float* fm0   = (float*)alloc((size_t)NB * NV * K0 * 4);
    float* feat1 = (float*)alloc((size_t)NB * NV * 8 * C1 * 4);
    float* fm1   = (float*)alloc((size_t)NB * NV * C1 * 4);
    float* v1    = (float*)alloc((size_t)NB * NV2 * 3 * 4);
    float* fm1p  = (float*)alloc((size_t)NB * NV2 * C1 * 4);
    int*   nbr2  = (int*)  alloc((size_t)NB * NV2 * NN * 4);
    float* feat2 = (float*)alloc((size_t)NB * NV2 * 8 * C2 * 4);
    float* fm2   = (float*)alloc((size_t)NB * NV2 * C2 * 4);

    v2_kernel<<<1, 384, 0, stream>>>(verts, out, pac);
    knn_coop_kernel<NV, NV / 256><<<NB * (NV / 4), 256, 0, stream>>>(verts, nbr1);
    op3d_kernel<<<64, 256, 0, stream>>>(verts, nbr1, w0w, w0d, fm0);
    feat_gemm<K0, 8 * C1><<<(NB * NV / 64) * (8 * C1 / 64), 256, 0, stream>>>(fm0, w1w, w1b, feat1);
    opnd1_gather<<<NB * NV / 4, 256, 0, stream>>>(verts, nbr1, feat1, w1d, fm1);
    pool1_kernel<<<NB * NV2 / 4, 256, 0, stream>>>(verts, nbr1, fm1, v1, fm1p, pa1);
    knn_coop_kernel<NV2, NV2 / 256><<<NB * (NV2 / 4), 256, 0, stream>>>(v1, nbr2);
    feat_gemm<C1, 8 * C2><<<(NB * NV2 / 64) * (8 * C2 / 64), 256, 0, stream>>>(fm1p, w2w, w2b, feat2);
    opnd2_gather<<<NB * NV2, 256, 0, stream>>>(v1, nbr2, feat2, w2d, fm2);
    pool2_kernel<<<32, 256, 0, stream>>>(nbr2, fm2, out, pa2);
}

// Round 35
// 221.087 us; speedup vs baseline: 1.0833x; 1.0833x over previous
//
#include <hip/hip_runtime.h>
#include <hip/hip_bf16.h>
#include <stdint.h>
#include <string.h>

// ---------------------------------------------------------------------------
// Problem constants
// ---------------------------------------------------------------------------
#define NB   8
#define NV   2048
#define NN   20      // NEIGHBOR_NUM
#define SUP  7       // SUPPORT
#define K0   32
#define C1   64
#define C2   256
#define NV2  256     // vertices after pooling 1
#define NP2  16      // vertices after pooling 2
#define COLL_CAP 320

// ---------------------------------------------------------------------------
// Permutations (proven R21..R34)
// ---------------------------------------------------------------------------
typedef unsigned __int128 u128;

struct CPcg { u128 state; u128 inc; bool has32; uint32_t cached; };

constexpr u128 PCG_MULT = (((u128)2549297995355413924ULL) << 64) | 4865540595714422341ULL;

constexpr uint64_t c_rotr64(uint64_t v, unsigned r) {
    return (v >> (r & 63u)) | (v << ((64u - r) & 63u));
}
constexpr uint64_t pcg_next64(CPcg& g) {
    g.state = g.state * PCG_MULT + g.inc;
    uint64_t hi = (uint64_t)(g.state >> 64);
    uint64_t lo = (uint64_t)g.state;
    return c_rotr64(hi ^ lo, (unsigned)(hi >> 58));
}
constexpr uint32_t pcg_next32(CPcg& g) {
    if (g.has32) { g.has32 = false; return g.cached; }
    uint64_t n = pcg_next64(g);
    g.has32 = true;
    g.cached = (uint32_t)(n >> 32);
    return (uint32_t)n;
}
constexpr uint64_t rand_interval(CPcg& g, uint64_t mx) {
    if (mx == 0) return 0;
    uint64_t mask = mx;
    mask |= mask >> 1; mask |= mask >> 2; mask |= mask >> 4;
    mask |= mask >> 8; mask |= mask >> 16; mask |= mask >> 32;
    uint64_t v = 0;
    while ((v = ((uint64_t)pcg_next32(g) & mask)) > mx) {
    }
    return v;
}
constexpr uint32_t hashmix(uint32_t value, uint32_t& hc) {
    value ^= hc; hc *= 0x931e8875u; value *= hc; value ^= value >> 16; return value;
}
constexpr uint32_t mixpool(uint32_t x, uint32_t y) {
    uint32_t r = (x * 0xca01f9ddu) - (y * 0x4973f715u);
    r ^= r >> 16; return r;
}
constexpr CPcg make_rng(uint32_t entropy) {
    uint32_t pool[4] = {0, 0, 0, 0};
    uint32_t hc = 0x43b0d7e5u;
    for (int i = 0; i < 4; i++) {
        uint32_t v = (i == 0) ? entropy : 0u;
        pool[i] = hashmix(v, hc);
    }
    for (int isrc = 0; isrc < 4; isrc++)
        for (int idst = 0; idst < 4; idst++)
            if (isrc != idst) pool[idst] = mixpool(pool[idst], hashmix(pool[isrc], hc));
    uint32_t w[8] = {};
    uint32_t hb = 0x8b51f9ddu;
    for (int i = 0; i < 8; i++) {
        uint32_t dv = pool[i & 3];
        dv ^= hb; hb *= 0x58f38dedu; dv *= hb; dv ^= dv >> 16; w[i] = dv;
    }
    uint64_t sd[4] = {};
    for (int k = 0; k < 4; k++) sd[k] = (uint64_t)w[2 * k] | ((uint64_t)w[2 * k + 1] << 32);
    u128 s = (((u128)sd[0]) << 64) | sd[1];
    u128 iq = (((u128)sd[2]) << 64) | sd[3];
    CPcg g{};
    g.state = 0;
    g.inc = (iq << 1) | 1;
    g.state = g.state * PCG_MULT + g.inc;
    g.state += s;
    g.state = g.state * PCG_MULT + g.inc;
    g.has32 = false; g.cached = 0;
    return g;
}

struct PermOut { int p1[256]; int p2[16]; };

constexpr PermOut compute_perms() {
    PermOut o{};
    {
        CPcg g = make_rng(1u);
        int arr[2048] = {};
        for (int i = 0; i < 2048; i++) arr[i] = i;
        for (int i = 2047; i >= 1; i--) {
            int j = (int)rand_interval(g, (uint64_t)i);
            int t = arr[i]; arr[i] = arr[j]; arr[j] = t;
        }
        for (int i = 0; i < 256; i++) o.p1[i] = arr[i];
    }
    {
        CPcg g = make_rng(2u);
        int arr[256] = {};
        for (int i = 0; i < 256; i++) arr[i] = i;
        for (int i = 255; i >= 1; i--) {
            int j = (int)rand_interval(g, (uint64_t)i);
            int t = arr[i]; arr[i] = arr[j]; arr[j] = t;
        }
        for (int i = 0; i < 16; i++) o.p2[i] = arr[i];
    }
    return o;
}

struct PermArg1 { int v[256]; };
struct PermArg2 { int v[16]; };

// ---------------------------------------------------------------------------
// K0: v2 (outputs[0]) = verts[:, p1[p2[j]], :] — f32
// ---------------------------------------------------------------------------
__global__ __launch_bounds__(384) void v2_kernel(const float* __restrict__ verts,
                                                 float* __restrict__ out,
                                                 PermArg2 cidx) {
    int t = threadIdx.x;
    if (t < NB * NP2 * 3) {
        int b = t / (NP2 * 3);
        int rem = t - b * (NP2 * 3);
        int j = rem / 3;
        int c = rem - j * 3;
        out[t] = verts[(b * NV + cidx.v[j]) * 3 + c];
    }
}

// ---------------------------------------------------------------------------
// KNN linear-bucket select, 2-WAVE GROUPS (R35): block = 2 groups x 2 waves;
// each group owns one row; CPL = N/128 = 16 keys/lane (no spill, vs 32 that
// spilled in R30-R33). Per-group hist/coll/cnt (128-thread contention, half
// of R34). Barrier schedule: zero+keys+wred -> sync -> hist -> sync ->
// scan+collect -> sync -> rank; 3 barriers serve 2 rows (1.5/row vs R34's 4).
// svq packs (x,y,z,qj) — proven bit-identical in R34.
// ---------------------------------------------------------------------------
template<int N, int CPL>
__global__ __launch_bounds__(256, 4) void knn_pair_kernel(const float* __restrict__ verts,
                                                          int* __restrict__ nbr) {
    __shared__ float4 svq[N];
    __shared__ int hist[2][256];
    __shared__ unsigned long long coll[2][COLL_CAP];
    __shared__ int cnt[2];
    __shared__ unsigned wred[2][4];   // [g][min0,min1,max0,max1]

    constexpr int RPG = 4;            // rows per group; block covers 2*RPG rows
    int bpb = N / (2 * RPG);
    int b = blockIdx.x / bpb;
    int rbase = (blockIdx.x % bpb) * (2 * RPG);

    const float* vb = verts + (size_t)b * N * 3;
    for (int t = threadIdx.x; t < N; t += 256) {
        float x = vb[t * 3 + 0], y = vb[t * 3 + 1], z = vb[t * 3 + 2];
        svq[t] = make_float4(x, y, z, x * x + y * y + z * z);  // same expr order
    }
    __syncthreads();

    int wid = threadIdx.x >> 6, lane = threadIdx.x & 63;
    int g = wid >> 1;                  // group 0/1
    int wg = wid & 1;                  // wave within group
    int tig = threadIdx.x & 127;       // thread within group
    int* myhist = hist[g];
    unsigned long long* mycoll = coll[g];

    for (int rr = 0; rr < RPG; rr++) {
        int i = rbase + g * RPG + rr;
        float4 vi = svq[i];
        float vx = vi.x, vy = vi.y, vz = vi.z;
        float qi = vi.w;

        // (a) zero own-group hist + cnt (visibility via the sync after (b))
        myhist[tig * 2 + 0] = 0;
        myhist[tig * 2 + 1] = 0;
        if (tig == 0) cnt[g] = 0;

        // (b) keys + wave min/max
        unsigned key[CPL];
        unsigned lmin = 0xFFFFFFFFu, lmax = 0u;
        #pragma unroll
        for (int t = 0; t < CPL; t++) {
            int j = wg * (CPL * 64) + t * 64 + lane;
            float4 vj = svq[j];
            float inner = vx * vj.x + vy * vj.y + vz * vj.z;
            float dist = (-2.0f * inner + qi) + vj.w;   // same expr as reference
            unsigned u = __float_as_uint(dist);
            u = (u & 0x80000000u) ? ~u : (u | 0x80000000u);  // monotone map
            if (j == i) u = 0xFFFFFFFFu;                      // self sentinel
            key[t] = u;
            if (u != 0xFFFFFFFFu) {
                lmin = (u < lmin) ? u : lmin;
                lmax = (u > lmax) ? u : lmax;
            }
        }
        #pragma unroll
        for (int off = 32; off >= 1; off >>= 1) {
            unsigned o1 = (unsigned)__shfl_xor((int)lmin, off);
            unsigned o2 = (unsigned)__shfl_xor((int)lmax, off);
            lmin = (o1 < lmin) ? o1 : lmin;
            lmax = (o2 > lmax) ? o2 : lmax;
        }
        if (lane == 0) { wred[g][wg] = lmin; wred[g][2 + wg] = lmax; }
        __syncthreads();   // #1: hist zeros + wred visible

        // (d) combine group min/max, histogram
        lmin = (wred[g][0] < wred[g][1]) ? wred[g][0] : wred[g][1];
        lmax = (wred[g][2] > wred[g][3]) ? wred[g][2] : wred[g][3];
        float scale = (lmax > lmin) ? 255.0f / (float)(lmax - lmin) : 0.0f;

        #pragma unroll
        for (int t = 0; t < CPL; t++) {
            int bi = (key[t] == 0xFFFFFFFFu) ? 255
                     : (int)((float)(key[t] - lmin) * scale);
            bi = (bi > 255) ? 255 : bi;
            atomicAdd(&myhist[bi], 1);
        }
        __syncthreads();   // #2: histogram complete

        // (f) per-wave redundant boundary search (identical in both waves)
        int h0 = myhist[lane * 4 + 0];
        int h1 = myhist[lane * 4 + 1];
        int h2 = myhist[lane * 4 + 2];
        int h3 = myhist[lane * 4 + 3];
        int s = h0 + h1 + h2 + h3;
        int cum = s;
        #pragma unroll
        for (int off = 1; off < 64; off <<= 1) {
            int v = __shfl_up(cum, off);
            if (lane >= off) cum += v;
        }
        unsigned long long bal = __ballot(cum >= NN);
        int L = __ffsll((long long)bal) - 1;
        int baseL = __shfl(cum, L) - __shfl(s, L);
        int g0 = __shfl(h0, L), g1 = __shfl(h1, L), g2 = __shfl(h2, L);
        int B;
        if (baseL + g0 >= NN)            B = 4 * L + 0;
        else if (baseL + g0 + g1 >= NN)  B = 4 * L + 1;
        else if (baseL + g0 + g1 + g2 >= NN) B = 4 * L + 2;
        else                              B = 4 * L + 3;

        // collect bins <= B into group coll
        #pragma unroll
        for (int t = 0; t < CPL; t++) {
            int bi = (key[t] == 0xFFFFFFFFu) ? 255
                     : (int)((float)(key[t] - lmin) * scale);
            bi = (bi > 255) ? 255 : bi;
            if (bi <= B) {
                int pos = atomicAdd(&cnt[g], 1);
                if (pos < COLL_CAP) {
                    int j = wg * (CPL * 64) + t * 64 + lane;
                    mycoll[pos] = ((unsigned long long)key[t] << 32) | (unsigned)j;
                }
            }
        }
        __syncthreads();   // #3: coll/cnt complete
        int count = cnt[g];
        if (count > COLL_CAP) count = COLL_CAP;

        // (h) exact rank pass over group's 128 threads
        int* dst = nbr + ((size_t)b * N + i) * NN;
        for (int e = tig; e < count; e += 128) {
            unsigned long long me = mycoll[e];
            int rank = 0;
            for (int m = 0; m < count; m++) rank += (mycoll[m] < me);
            if (rank < NN) dst[rank] = (int)(me & 0xFFFFFFFFull);
        }
        // next iteration's (a) touches hist/cnt only; coll reads above use
        // registers + mycoll which (a) does not write. No barrier needed here.
    }
}

// ---------------------------------------------------------------------------
// K2: operator3d + relu -> fm0 (8,2048,32). One thread per vertex.
// ---------------------------------------------------------------------------
__global__ __launch_bounds__(256) void op3d_kernel(const float* __restrict__ verts,
                                                   const int* __restrict__ nbr,
                                                   const float* __restrict__ w0w,
                                                   const float* __restrict__ w0d,
                                                   float* __restrict__ fm0) {
    __shared__ float swd[3 * SUP * K0];
    __shared__ float sww[SUP * K0];
    for (int t = threadIdx.x; t < 3 * SUP * K0; t += 256) swd[t] = w0d[t];
    for (int t = threadIdx.x; t < SUP * K0; t += 256) sww[t] = w0w[t];
    __syncthreads();

    int gid = blockIdx.x * 256 + threadIdx.x;
    int b = gid >> 11, v = gid & (NV - 1);
    const float* vb = verts + b * NV * 3;
    float vx = vb[v * 3], vy = vb[v * 3 + 1], vz = vb[v * 3 + 2];

    const int* nb = nbr + gid * NN;
    float dx[NN], dy[NN], dz[NN];
    #pragma unroll
    for (int n = 0; n < NN; n++) {
        int j = nb[n];
        dx[n] = vb[j * 3 + 0] - vx;
        dy[n] = vb[j * 3 + 1] - vy;
        dz[n] = vb[j * 3 + 2] - vz;
    }
    float* out = fm0 + gid * K0;
    #pragma unroll 1
    for (int k = 0; k < K0; k++) {
        float acc = 0.f;
        #pragma unroll
        for (int s = 0; s < SUP; s++) {
            float w0 = swd[0 * 224 + s * K0 + k];
            float w1 = swd[1 * 224 + s * K0 + k];
            float w2 = swd[2 * 224 + s * K0 + k];
            float m = 0.f;
            #pragma unroll
            for (int n = 0; n < NN; n++) {
                float t = dx[n] * w0 + dy[n] * w1 + dz[n] * w2;
                t = fmaxf(t, 0.f);
                m = fmaxf(m, t);
            }
            acc += m * sww[s * K0 + k];
        }
        out[k] = fmaxf(acc, 0.f);
    }
}

// ---------------------------------------------------------------------------
// feat GEMM (R27, proven)
// ---------------------------------------------------------------------------
template<int K, int N>
__global__ __launch_bounds__(256) void feat_gemm(const float* __restrict__ fm,
                                                 const float* __restrict__ w,
                                                 const float* __restrict__ bias,
                                                 float* __restrict__ feat) {
    __shared__ float sf[64][K];
    __shared__ float swt[K][64];
    int cb = blockIdx.x % (N / 64), rb = blockIdx.x / (N / 64);
    int r0 = rb * 64, c0 = cb * 64;

    for (int t = threadIdx.x; t < 64 * K; t += 256)
        sf[t / K][t % K] = fm[(size_t)(r0 + t / K) * K + (t % K)];
    for (int t = threadIdx.x; t < K * 64; t += 256)
        swt[t >> 6][t & 63] = w[(size_t)(t >> 6) * N + c0 + (t & 63)];
    __syncthreads();

    int col = threadIdx.x & 63, rg = threadIdx.x >> 6;
    float bv = bias[c0 + col];
    float acc[16];
    #pragma unroll
    for (int r = 0; r < 16; r++) acc[r] = bv;
    #pragma unroll 1
    for (int k = 0; k < K; k++) {
        float wk = swt[k][col];
        #pragma unroll
        for (int r = 0; r < 16; r++) acc[r] += sf[rg * 16 + r][k] * wk;
    }
    #pragma unroll
    for (int r = 0; r < 16; r++)
        feat[(size_t)(r0 + rg * 16 + r) * N + c0 + col] = acc[r];
}

// ---------------------------------------------------------------------------
// opnd1 gather-max (n-outer, unroll 4) + XCD swizzle (R33, proven)
// ---------------------------------------------------------------------------
__global__ __launch_bounds__(256) void opnd1_gather(const float* __restrict__ verts,
                                                    const int* __restrict__ nbr,
                                                    const float* __restrict__ feat1,
                                                    const float* __restrict__ w1d,
                                                    float* __restrict__ fm1) {
    __shared__ float swd[3 * SUP * C1];
    for (int t = threadIdx.x; t < 3 * SUP * C1; t += 256) swd[t] = w1d[t];
    __syncthreads();

    int wid = threadIdx.x >> 6, lane = threadIdx.x & 63;
    int b = blockIdx.x & 7;
    int vtx = b * NV + (blockIdx.x >> 3) * 4 + wid;
    int v = vtx & (NV - 1);
    const float* vb = verts + b * NV * 3;
    const int* nb = nbr + vtx * NN;
    float vx = vb[v * 3], vy = vb[v * 3 + 1], vz = vb[v * 3 + 2];

    float w0r[SUP], w1r[SUP], w2r[SUP];
    #pragma unroll
    for (int ss = 0; ss < SUP; ss++) {
        w0r[ss] = swd[0 * (SUP * C1) + ss * C1 + lane];
        w1r[ss] = swd[1 * (SUP * C1) + ss * C1 + lane];
        w2r[ss] = swd[2 * (SUP * C1) + ss * C1 + lane];
    }

    const float* fb = feat1 + (size_t)b * NV * (8 * C1);
    float m[SUP];
    #pragma unroll
    for (int ss = 0; ss < SUP; ss++) m[ss] = -3.4e38f;

    #pragma unroll 4
    for (int n = 0; n < NN; n++) {
        int j = nb[n];
        float dx = vb[j * 3 + 0] - vx;
        float dy = vb[j * 3 + 1] - vy;
        float dz = vb[j * 3 + 2] - vz;
        const float* row = fb + (size_t)j * (8 * C1) + C1 + lane;
        #pragma unroll
        for (int ss = 0; ss < SUP; ss++) {
            float th = fmaxf(dx * w0r[ss] + dy * w1r[ss] + dz * w2r[ss], 0.f);
            m[ss] = fmaxf(m[ss], th * row[ss * C1]);
        }
    }
    float fcen = fb[(size_t)v * (8 * C1) + lane];
    float total = 0.f;
    #pragma unroll
    for (int ss = 0; ss < SUP; ss++) total += m[ss];
    fm1[vtx * C1 + lane] = fmaxf(fcen + total, 0.f);
}

// ---------------------------------------------------------------------------
// opnd2 gather-max: one wave per (vertex, jj) + XCD swizzle (R33, proven)
// ---------------------------------------------------------------------------
__global__ __launch_bounds__(256) void opnd2_gather(const float* __restrict__ v1,
                                                    const int* __restrict__ nbr2,
                                                    const float* __restrict__ feat2,
                                                    const float* __restrict__ w2d,
                                                    float* __restrict__ fm2) {
    __shared__ float swd[3 * SUP * C2];
    for (int t = threadIdx.x; t < 3 * SUP * C2; t += 256) swd[t] = w2d[t];
    __syncthreads();

    int jj = threadIdx.x >> 6, lane = threadIdx.x & 63;
    int b = blockIdx.x & 7;
    int v = blockIdx.x >> 3;
    int vtx = b * NV2 + v;
    const float* vb = v1 + b * NV2 * 3;
    const int* nb = nbr2 + vtx * NN;
    float vx = vb[v * 3], vy = vb[v * 3 + 1], vz = vb[v * 3 + 2];

    int cj = jj * 64 + lane;
    float w0r[SUP], w1r[SUP], w2r[SUP];
    #pragma unroll
    for (int ss = 0; ss < SUP; ss++) {
        w0r[ss] = swd[0 * (SUP * C2) + ss * C2 + cj];
        w1r[ss] = swd[1 * (SUP * C2) + ss * C2 + cj];
        w2r[ss] = swd[2 * (SUP * C2) + ss * C2 + cj];
    }
    const float* fb = feat2 + (size_t)b * NV2 * (8 * C2);

    float m[SUP];
    #pragma unroll
    for (int ss = 0; ss < SUP; ss++) m[ss] = -3.4e38f;

    #pragma unroll 4
    for (int n = 0; n < NN; n++) {
        int j = nb[n];
        float dx = vb[j * 3 + 0] - vx;
        float dy = vb[j * 3 + 1] - vy;
        float dz = vb[j * 3 + 2] - vz;
        const float* row = fb + (size_t)j * (8 * C2) + C2 + cj;
        #pragma unroll
        for (int ss = 0; ss < SUP; ss++) {
            float th = fmaxf(dx * w0r[ss] + dy * w1r[ss] + dz * w2r[ss], 0.f);
            m[ss] = fmaxf(m[ss], th * row[ss * C2]);
        }
    }
    float total = 0.f;
    #pragma unroll
    for (int ss = 0; ss < SUP; ss++) total += m[ss];
    float fcen = fb[(size_t)v * (8 * C2) + cj];
    fm2[(size_t)vtx * C2 + cj] = fmaxf(fcen + total, 0.f);
}

// ---------------------------------------------------------------------------
// K5: pooling 1 -> v1, fm1p. One wave per sampled vertex.
// ---------------------------------------------------------------------------
__global__ __launch_bounds__(256) void pool1_kernel(const float* __restrict__ verts,
                                                    const int* __restrict__ nbr1,
                                                    const float* __restrict__ fm1,
                                                    float* __restrict__ v1,
                                                    float* __restrict__ fm1p,
                                                    PermArg1 pa) {
    int wid = threadIdx.x >> 6, lane = threadIdx.x & 63;
    int gid = blockIdx.x * 4 + wid;
    int b = gid >> 8, p = gid & 255;
    int sv = pa.v[p];
    const int* nb = nbr1 + (b * NV + sv) * NN;
    float m = -3.4e38f;
    #pragma unroll
    for (int n = 0; n < 8; n++) {
        m = fmaxf(m, fm1[(b * NV + nb[n]) * C1 + lane]);
    }
    fm1p[gid * C1 + lane] = m;
    if (lane < 3) v1[gid * 3 + lane] = verts[(b * NV + sv) * 3 + lane];
}

// ---------------------------------------------------------------------------
// K9: pooling 2 -> fm3 (outputs[1]) — f32
// ---------------------------------------------------------------------------
__global__ __launch_bounds__(256) void pool2_kernel(const int* __restrict__ nbr2,
                                                    const float* __restrict__ fm2,
                                                    float* __restrict__ out,
                                                    PermArg2 pa) {
    int wid = threadIdx.x >> 6, lane = threadIdx.x & 63;
    int gid = blockIdx.x * 4 + wid;
    int b = gid >> 4, p = gid & 15;
    int sv = pa.v[p];
    const int* nb = nbr2 + (b * NV2 + sv) * NN;
    #pragma unroll 1
    for (int jj = 0; jj < 4; jj++) {
        int c = lane + jj * 64;
        float m = -3.4e38f;
        #pragma unroll
        for (int n = 0; n < 16; n++) {
            m = fmaxf(m, fm2[(b * NV2 + nb[n]) * C2 + c]);
        }
        out[NB * NP2 * 3 + gid * C2 + c] = m;
    }
}

// ---------------------------------------------------------------------------
// Launch
// ---------------------------------------------------------------------------
extern "C" void kernel_launch(void* const* d_in, const int* in_sizes, int n_in,
                              void* d_out, int out_size, void* d_ws, size_t ws_size,
                              hipStream_t stream) {
    (void)in_sizes; (void)n_in; (void)out_size; (void)ws_size;
    const float* verts = (const float*)d_in[0];
    const float* w0w = (const float*)d_in[1];
    const float* w0d = (const float*)d_in[2];
    const float* w1w = (const float*)d_in[3];
    const float* w1b = (const float*)d_in[4];
    const float* w1d = (const float*)d_in[5];
    const float* w2w = (const float*)d_in[6];
    const float* w2b = (const float*)d_in[7];
    const float* w2d = (const float*)d_in[8];
    float* out = (float*)d_out;

    static const PermOut perms = compute_perms();

    PermArg1 pa1;
    PermArg2 pa2, pac;
    memcpy(pa1.v, perms.p1, sizeof(pa1.v));
    memcpy(pa2.v, perms.p2, sizeof(pa2.v));
    for (int j = 0; j < 16; j++) pac.v[j] = perms.p1[perms.p2[j]];

    char* ws = (char*)d_ws;
    size_t off = 0;
    auto alloc = [&](size_t bytes) -> void* {
        void* p = ws + off;
        off += (bytes + 255) & ~(size_t)255;
        return p;
    };
    int*   nbr1  = (int*)  alloc((size_t)NB * NV * NN * 4);
    float* fm0   = (float*)alloc((size_t)NB * NV * K0 * 4);
    float* feat1 = (float*)alloc((size_t)NB * NV * 8 * C1 * 4);
    float* fm1   = (float*)alloc((size_t)NB * NV * C1 * 4);
    float* v1    = (float*)alloc((size_t)NB * NV2 * 3 * 4);
    float* fm1p  = (float*)alloc((size_t)NB * NV2 * C1 * 4);
    int*   nbr2  = (int*)  alloc((size_t)NB * NV2 * NN * 4);
    float* feat2 = (float*)alloc((size_t)NB * NV2 * 8 * C2 * 4);
    float* fm2   = (float*)alloc((size_t)NB * NV2 * C2 * 4);

    v2_kernel<<<1, 384, 0, stream>>>(verts, out, pac);
    knn_pair_kernel<NV, NV / 128><<<NB * (NV / 8), 256, 0, stream>>>(verts, nbr1);
    op3d_kernel<<<64, 256, 0, stream>>>(verts, nbr1, w0w, w0d, fm0);
    feat_gemm<K0, 8 * C1><<<(NB * NV / 64) * (8 * C1 / 64), 256, 0, stream>>>(fm0, w1w, w1b, feat1);
    opnd1_gather<<<NB * NV / 4, 256, 0, stream>>>(verts, nbr1, feat1, w1d, fm1);
    pool1_kernel<<<NB * NV2 / 4, 256, 0, stream>>>(verts, nbr1, fm1, v1, fm1p, pa1);
    knn_pair_kernel<NV2, NV2 / 128><<<NB * (NV2 / 8), 256, 0, stream>>>(v1, nbr2);
    feat_gemm<C1, 8 * C2><<<(NB * NV2 / 64) * (8 * C2 / 64), 256, 0, stream>>>(fm1p, w2w, w2b, feat2);
    opnd2_gather<<<NB * NV2, 256, 0, stream>>>(v1, nbr2, feat2, w2d, fm2);
    pool2_kernel<<<32, 256, 0, stream>>>(nbr2, fm2, out, pa2);
}